// Round 8
// baseline (2441.044 us; speedup 1.0000x reference)
//
#include <hip/hip_runtime.h>
#include <stdint.h>

// Problem constants (SimpleRNN reference)
#define VOCAB 50000
#define D     512
#define LSEQ  512
#define BATCH 256
#define NCLS  20

typedef unsigned short u16;
typedef uint32_t u32;
using f32x4 = __attribute__((ext_vector_type(4))) float;
using s16x8 = __attribute__((ext_vector_type(8))) short;
using u32x2 = __attribute__((ext_vector_type(2))) unsigned int;
using u32x4 = __attribute__((ext_vector_type(4))) unsigned int;

__device__ __forceinline__ u16 f2bf(float f){
  uint32_t x = __float_as_uint(f);
  x += 0x7fffu + ((x >> 16) & 1u);          // RNE
  return (u16)(x >> 16);
}
__device__ __forceinline__ float bflo(uint32_t u){ return __uint_as_float(u << 16); }
__device__ __forceinline__ float bfhi(uint32_t u){ return __uint_as_float(u & 0xffff0000u); }
__device__ __forceinline__ float fast_tanh(float x){
  float e = __builtin_amdgcn_exp2f(x * 2.8853900817779268f);   // e^(2x)
  return 1.0f - 2.0f * __builtin_amdgcn_rcpf(1.0f + e);
}
// lgkm-only barrier: orders LDS writes/reads across threads without draining
// vmcnt (no vmem ordering is needed across it — exchange is tag-validated,
// xin waits are compiler-managed at use).
__device__ __forceinline__ void barrier_lds(){
  asm volatile("s_waitcnt lgkmcnt(0)\n\ts_barrier" ::: "memory");
}

// LDS B-frag layout with pad: elem(k,n) at (k>>5)*544 + ((k>>3)&3)*136 + n*8 + (k&7)
#define CG   544
#define QD   136

// ---------------------------------------------------------------------------
// Kernel 0: transpose + bf16-convert Wx and Wh -> [n][k] layout.
// ---------------------------------------------------------------------------
__global__ void k_transpose_cvt(const float* __restrict__ Wx, const float* __restrict__ Wh,
                                u16* __restrict__ Wxt, u16* __restrict__ Wht){
  const int n = blockIdx.x & 511;
  const float* src = (blockIdx.x >> 9) ? Wh : Wx;
  u16* dst = (blockIdx.x >> 9) ? Wht : Wxt;
  for (int k = threadIdx.x; k < D; k += blockDim.x)
    dst[n * D + k] = f2bf(src[k * D + n]);
}

// ---------------------------------------------------------------------------
// Kernel 1: xin[l][b][:] = emb[x[b][l]] @ Wx + b   (stored bf16, [L][B][D])
// ---------------------------------------------------------------------------
__launch_bounds__(256, 2)
__global__ void k_xin(const int* __restrict__ x, const float* __restrict__ emb,
                      const u16* __restrict__ Wxt, const float* __restrict__ bias,
                      u16* __restrict__ xin){
  __shared__ __align__(16) u16 Bt_s[512 * 40];
  __shared__ int tok_s[64];
  const int tid  = threadIdx.x;
  const int lane = tid & 63, w = tid >> 6;
  const int nl   = lane & 15, q = lane >> 4;
  const int m0   = blockIdx.x * 64;

  if (tid < 64){
    int R = m0 + tid;
    int l = R >> 8, b = R & 255;
    tok_s[tid] = x[b * LSEQ + l];
  }
  f32x4 acc[32];
  #pragma unroll
  for (int i = 0; i < 32; ++i) acc[i] = (f32x4)0.0f;
  __syncthreads();

  const int myrow = 16 * w + nl;
  const float* arow = emb + (size_t)tok_s[myrow] * D;

  for (int kc = 0; kc < 16; ++kc){
    #pragma unroll
    for (int i = 0; i < 8; ++i){
      int idx = tid + 256 * i;
      int r = idx >> 2, cc = idx & 3;
      *(uint4*)&Bt_s[r * 40 + cc * 8] = *(const uint4*)(Wxt + r * D + kc * 32 + cc * 8);
    }
    __syncthreads();
    float4 f0 = *(const float4*)(arow + kc * 32 + q * 8);
    float4 f1 = *(const float4*)(arow + kc * 32 + q * 8 + 4);
    s16x8 a;
    a[0]=(short)f2bf(f0.x); a[1]=(short)f2bf(f0.y); a[2]=(short)f2bf(f0.z); a[3]=(short)f2bf(f0.w);
    a[4]=(short)f2bf(f1.x); a[5]=(short)f2bf(f1.y); a[6]=(short)f2bf(f1.z); a[7]=(short)f2bf(f1.w);
    #pragma unroll
    for (int nt = 0; nt < 32; ++nt){
      s16x8 b = *(const s16x8*)&Bt_s[(16 * nt + nl) * 40 + q * 8];
      acc[nt] = __builtin_amdgcn_mfma_f32_16x16x32_bf16(a, b, acc[nt], 0, 0, 0);
    }
    __syncthreads();
  }
  const int rowbase = m0 + 16 * w + 4 * q;
  #pragma unroll
  for (int nt = 0; nt < 32; ++nt){
    int col = 16 * nt + nl;
    float bc = bias[col];
    #pragma unroll
    for (int r = 0; r < 4; ++r)
      xin[(size_t)(rowbase + r) * D + col] = f2bf(acc[nt][r] + bc);
  }
}

// ---------------------------------------------------------------------------
// Kernel 2: recurrence. 32 blocks = 8 groups (32 rows) x 4 col-slices
// (128 cols; whA[2][16] resident via intrinsics). Two 16-row sub-batches
// interleaved. Exchange: tagged u32 (bf16<<16 | step_tag), parity buffers.
// SOUNDNESS RULES (R7 post-mortem): no counted vmcnt anywhere. Tagged-chunk
// prefetch carries NO wait — any stale register observation fails the tag
// check and the retry block (vmcnt(0) INSIDE the asm) re-loads; payload rides
// in the same 32-bit word as its tag, so tag-valid => payload-valid. xin uses
// plain C++ loads (compiler-managed waits: FIFO vmcnt retirement makes its
// counted waits conservative-correct even with untracked asm vmem newer than
// its loads). Own slice passes through registers (ownpk). No memset needed:
// poison tag 0xAAAA never equals a step tag; h(0)=0 via skipping MFMA at t=0.
// ---------------------------------------------------------------------------
__launch_bounds__(256, 1)
__global__ void k_rnn(const u16* __restrict__ xin, const u16* __restrict__ Wht,
                      u32* __restrict__ hx, float* __restrict__ hlast){
  __shared__ __align__(16) u16 h_s[2][16 * CG];   // one buffer per sub
  const int tid  = threadIdx.x;
  const int lane = tid & 63, w = tid >> 6;        // 4 waves
  const int nl   = lane & 15, q = lane >> 4;
  const int g    = blockIdx.x >> 2;               // 8 groups
  const int j    = blockIdx.x & 3;                // 4 slices
  const int grow = g * 32;
  const int colbase = j * 128 + w * 32;

  // resident Wh A-fragments (intrinsics -> compiler-managed hazards/AGPRs)
  s16x8 whA[2][16];
  #pragma unroll
  for (int mt = 0; mt < 2; ++mt){
    const u16* wrow = Wht + (size_t)(colbase + 16 * mt + nl) * D;
    #pragma unroll
    for (int kc = 0; kc < 16; ++kc)
      whA[mt][kc] = *(const s16x8*)(wrow + kc * 32 + q * 8);
  }

  // foreign chunks: 3 slices x (16 rows x 32 four-col chunks), 6 per thread
  int f_off[6], f_sidx[6];
  #pragma unroll
  for (int i = 0; i < 6; ++i){
    int idx = tid + 256 * (i & 1);
    int js  = (j + 1 + (i >> 1)) & 3;
    int r   = idx >> 5, cc = idx & 31;
    int col = js * 128 + cc * 4;
    f_off[i]  = r * 512 + col;
    f_sidx[i] = (col >> 5) * CG + ((col >> 3) & 3) * QD + r * 8 + (col & 7);
  }
  int cb[2], own_sidx[2], own_off[2];
  #pragma unroll
  for (int mt = 0; mt < 2; ++mt){
    cb[mt]       = colbase + 16 * mt + 4 * q;
    own_sidx[mt] = (cb[mt] >> 5) * CG + ((cb[mt] >> 3) & 3) * QD + nl * 8 + (cb[mt] & 7);
    own_off[mt]  = nl * 512 + cb[mt];
  }
  const int rdoff = q * QD + nl * 8;

  u32* hxb[2][2];
  #pragma unroll
  for (int s = 0; s < 2; ++s)
    #pragma unroll
    for (int p = 0; p < 2; ++p)
      hxb[s][p] = hx + (((s * 2 + p) * 8 + g) << 13);

  u32x4 pf[2][6];     // prefetched tagged chunks per sub (tag-validated)
  u32x2 ownpk[2][2];  // own h-slice in LDS format, carried in registers

  #define TAGBAD(cv, tt) ((((cv)[0]^(tt))|((cv)[1]^(tt))|((cv)[2]^(tt))|((cv)[3]^(tt))) & 0xffffu)

  for (int t = 0; t < LSEQ; ++t){
    #pragma unroll
    for (int s = 0; s < 2; ++s){
      // xin: plain cached loads, compiler-managed wait at use (acc init)
      const u16* xp = xin + ((size_t)t * BATCH + grow + 16 * s + nl) * D + colbase + 4 * q;
      u32x2 xa = *(const u32x2*)(xp);
      u32x2 xb = *(const u32x2*)(xp + 16);

      if (t > 0){
        const u32 tt = (u32)t;
        const u32* pb = hxb[s][t & 1];
        // validate prefetched regs directly — staleness caught by tags
        u32 bad = TAGBAD(pf[s][0],tt) | TAGBAD(pf[s][1],tt) | TAGBAD(pf[s][2],tt)
                | TAGBAD(pf[s][3],tt) | TAGBAD(pf[s][4],tt) | TAGBAD(pf[s][5],tt);
        while (__builtin_expect(bad != 0, 0)){
          asm volatile(
            "global_load_dwordx4 %0, %6, off sc0 sc1\n\t"
            "global_load_dwordx4 %1, %7, off sc0 sc1\n\t"
            "global_load_dwordx4 %2, %8, off sc0 sc1\n\t"
            "global_load_dwordx4 %3, %9, off sc0 sc1\n\t"
            "global_load_dwordx4 %4, %10, off sc0 sc1\n\t"
            "global_load_dwordx4 %5, %11, off sc0 sc1\n\t"
            "s_waitcnt vmcnt(0)"                 // self-draining: outputs valid
            : "=&v"(pf[s][0]), "=&v"(pf[s][1]), "=&v"(pf[s][2]),
              "=&v"(pf[s][3]), "=&v"(pf[s][4]), "=&v"(pf[s][5])
            : "v"(pb + f_off[0]), "v"(pb + f_off[1]), "v"(pb + f_off[2]),
              "v"(pb + f_off[3]), "v"(pb + f_off[4]), "v"(pb + f_off[5])
            : "memory");
          bad = TAGBAD(pf[s][0],tt) | TAGBAD(pf[s][1],tt) | TAGBAD(pf[s][2],tt)
              | TAGBAD(pf[s][3],tt) | TAGBAD(pf[s][4],tt) | TAGBAD(pf[s][5],tt);
        }
        // stage foreign (bf16 = top16) + own slice from registers
        #pragma unroll
        for (int i = 0; i < 6; ++i){
          u32x2 pk;
          pk[0] = (pf[s][i][0] >> 16) | (pf[s][i][1] & 0xffff0000u);
          pk[1] = (pf[s][i][2] >> 16) | (pf[s][i][3] & 0xffff0000u);
          *(u32x2*)&h_s[s][f_sidx[i]] = pk;
        }
        *(u32x2*)&h_s[s][own_sidx[0]] = ownpk[s][0];
        *(u32x2*)&h_s[s][own_sidx[1]] = ownpk[s][1];
      }
      barrier_lds();

      // acc init from xin (R2 association: c = xin, MFMA accumulates on top)
      f32x4 acc[2];
      acc[0][0] = bflo(xa[0]); acc[0][1] = bfhi(xa[0]);
      acc[0][2] = bflo(xa[1]); acc[0][3] = bfhi(xa[1]);
      acc[1][0] = bflo(xb[0]); acc[1][1] = bfhi(xb[0]);
      acc[1][2] = bflo(xb[1]); acc[1][3] = bfhi(xb[1]);

      if (t > 0){
        #pragma unroll
        for (int kc = 0; kc < 16; ++kc){
          s16x8 hB = *(const s16x8*)&h_s[s][kc * CG + rdoff];
          acc[0] = __builtin_amdgcn_mfma_f32_16x16x32_bf16(whA[0][kc], hB, acc[0], 0, 0, 0);
          acc[1] = __builtin_amdgcn_mfma_f32_16x16x32_bf16(whA[1][kc], hB, acc[1], 0, 0, 0);
        }
      }

      const u32 tag = (u32)(t + 1);
      #pragma unroll
      for (int mt = 0; mt < 2; ++mt){
        float v0 = fast_tanh(acc[mt][0]);
        float v1 = fast_tanh(acc[mt][1]);
        float v2 = fast_tanh(acc[mt][2]);
        float v3 = fast_tanh(acc[mt][3]);
        if (t < LSEQ - 1){
          u16 b0 = f2bf(v0), b1 = f2bf(v1), b2 = f2bf(v2), b3 = f2bf(v3);
          ownpk[s][mt][0] = (u32)b0 | ((u32)b1 << 16);
          ownpk[s][mt][1] = (u32)b2 | ((u32)b3 << 16);
          u32x4 st;
          st[0] = ((u32)b0 << 16) | tag; st[1] = ((u32)b1 << 16) | tag;
          st[2] = ((u32)b2 << 16) | tag; st[3] = ((u32)b3 << 16) | tag;
          asm volatile("global_store_dwordx4 %0, %1, off sc0 sc1"
                       :: "v"(hxb[s][(t + 1) & 1] + own_off[mt]), "v"(st) : "memory");
        } else {
          *(float4*)(hlast + (size_t)(grow + 16 * s + nl) * D + cb[mt]) =
              make_float4(v0, v1, v2, v3);
        }
      }
      // prefetch next same-sub exchange — NO wait (tag-protected)
      if (t < LSEQ - 1){
        const u32* nb = hxb[s][(t + 1) & 1];
        asm volatile(
          "global_load_dwordx4 %0, %6, off sc0 sc1\n\t"
          "global_load_dwordx4 %1, %7, off sc0 sc1\n\t"
          "global_load_dwordx4 %2, %8, off sc0 sc1\n\t"
          "global_load_dwordx4 %3, %9, off sc0 sc1\n\t"
          "global_load_dwordx4 %4, %10, off sc0 sc1\n\t"
          "global_load_dwordx4 %5, %11, off sc0 sc1"
          : "=&v"(pf[s][0]), "=&v"(pf[s][1]), "=&v"(pf[s][2]),
            "=&v"(pf[s][3]), "=&v"(pf[s][4]), "=&v"(pf[s][5])
          : "v"(nb + f_off[0]), "v"(nb + f_off[1]), "v"(nb + f_off[2]),
            "v"(nb + f_off[3]), "v"(nb + f_off[4]), "v"(nb + f_off[5])
          : "memory");
      }
    }
  }
  #undef TAGBAD
}

// ---------------------------------------------------------------------------
// Kernel 3: logits = h_last @ Wd + bd; softmax. One wave per batch row.
// ---------------------------------------------------------------------------
__global__ void k_head(const float* __restrict__ hlast, const float* __restrict__ Wd,
                       const float* __restrict__ bd, float* __restrict__ out){
  const int b = blockIdx.x;
  const int lane = threadIdx.x;
  const float* hr = hlast + (size_t)b * D + lane * 8;
  float hv[8];
  #pragma unroll
  for (int i = 0; i < 8; ++i) hv[i] = hr[i];
  float acc[NCLS];
  #pragma unroll
  for (int c = 0; c < NCLS; ++c) acc[c] = 0.0f;
  #pragma unroll
  for (int i = 0; i < 8; ++i){
    const float* wr = Wd + (size_t)(lane * 8 + i) * NCLS;
    #pragma unroll
    for (int c = 0; c < NCLS; ++c) acc[c] += hv[i] * wr[c];
  }
  #pragma unroll
  for (int off = 32; off >= 1; off >>= 1){
    #pragma unroll
    for (int c = 0; c < NCLS; ++c) acc[c] += __shfl_xor(acc[c], off, 64);
  }
  float mx = -1e30f;
  #pragma unroll
  for (int c = 0; c < NCLS; ++c){ acc[c] += bd[c]; mx = fmaxf(mx, acc[c]); }
  float e[NCLS]; float s = 0.0f;
  #pragma unroll
  for (int c = 0; c < NCLS; ++c){
    e[c] = __builtin_amdgcn_exp2f((acc[c] - mx) * 1.4426950408889634f);
    s += e[c];
  }
  if (lane < NCLS) out[b * NCLS + lane] = e[lane] / s;
}

// ---------------------------------------------------------------------------
extern "C" void kernel_launch(void* const* d_in, const int* in_sizes, int n_in,
                              void* d_out, int out_size, void* d_ws, size_t ws_size,
                              hipStream_t stream){
  const int*   x    = (const int*)  d_in[0];
  const float* emb  = (const float*)d_in[1];
  const float* Wx   = (const float*)d_in[2];
  const float* Wh   = (const float*)d_in[3];
  const float* bias = (const float*)d_in[4];
  const float* Wd   = (const float*)d_in[5];
  const float* bd   = (const float*)d_in[6];
  float* out = (float*)d_out;
  char* ws = (char*)d_ws;

  const size_t XIN_B = (size_t)LSEQ * BATCH * D * 2;   // 134217728
  const size_t W_B   = (size_t)D * D * 2;              // 524288
  // hx: 2 subs x 2 parity x 8 groups x 16x512 u32 = 1 MiB tagged exchange

  u16*   xin   = (u16*)(ws);
  u16*   Wxt   = (u16*)(ws + XIN_B);            // dead after k_xin ...
  float* hlast = (float*)(ws + XIN_B);          // ... reused as hlast
  u16*   Wht   = (u16*)(ws + XIN_B + W_B);
  u32*   hx    = (u32*)(ws + XIN_B + 2 * W_B);
  (void)in_sizes; (void)n_in; (void)out_size; (void)ws_size;

  k_transpose_cvt<<<dim3(1024), dim3(256), 0, stream>>>(Wx, Wh, Wxt, Wht);
  k_xin          <<<dim3(2048), dim3(256), 0, stream>>>(x, emb, Wxt, bias, xin);
  k_rnn          <<<dim3(32),   dim3(256), 0, stream>>>(xin, Wht, hx, hlast);
  k_head         <<<dim3(256),  dim3(64),  0, stream>>>(hlast, Wd, bd, out);
}